// Round 1
// baseline (164.475 us; speedup 1.0000x reference)
//
#include <hip/hip_runtime.h>
#include <hip/hip_bf16.h>

// Block-diagonal matmul: out[t, n*64+e] = sum_d inp[t, n*64+d] * blocks[n, d, e]
// T=16384, 64 blocks of 64x64, fp32 in/out, bf16 MFMA compute (threshold 1.005).

typedef __attribute__((ext_vector_type(8))) short short8;   // 8 bf16 (4 VGPRs)
typedef __attribute__((ext_vector_type(4))) float f32x4;    // MFMA accumulator

#define D_TOT 4096      // 64 blocks * 64
#define LDSW  72        // padded bf16 stride for W^T rows (144 B -> 2-way bank alias, free)

__device__ __forceinline__ short f2b(float x) {
    union { __hip_bfloat16 h; short s; } u;
    u.h = __float2bfloat16(x);
    return u.s;
}

__global__ __launch_bounds__(512) void block_linear_kernel(
    const float* __restrict__ inp,
    const float* __restrict__ blocks,
    float* __restrict__ out)
{
    __shared__ __align__(16) __hip_bfloat16 WT[64 * LDSW];  // WT[e][d], bf16

    const int n   = blockIdx.y;       // which 64x64 block
    const int rt  = blockIdx.x;       // 128-row tile
    const int tid = threadIdx.x;

    // ---- Stage W[n]^T into LDS as bf16 (4096 elems / 512 threads = 8 each) ----
    const float* Wn = blocks + (size_t)n * 64 * 64;
    #pragma unroll
    for (int i = 0; i < 8; ++i) {
        int idx = tid + 512 * i;        // = d*64 + e   (coalesced global read)
        int d = idx >> 6, e = idx & 63;
        WT[e * LDSW + d] = __float2bfloat16(Wn[idx]);
    }
    __syncthreads();

    const int wave = tid >> 6;          // 0..7: 16-row strip per wave
    const int lane = tid & 63;
    const int g    = lane >> 4;         // k-group (0..3)
    const int lr   = lane & 15;         // A-row / B-col within 16x16 tile

    const int row0 = rt * 128 + wave * 16;
    const float* arow = inp + (size_t)(row0 + lr) * D_TOT + n * 64;

    // ---- A fragments: lane covers k = 32*s + 8*g + [0..7], global->reg ----
    short8 afrag[2];
    #pragma unroll
    for (int s = 0; s < 2; ++s) {
        const f32x4* p = (const f32x4*)(arow + 32 * s + 8 * g);
        f32x4 v0 = p[0];
        f32x4 v1 = p[1];
        short8 a;
        a[0] = f2b(v0[0]); a[1] = f2b(v0[1]); a[2] = f2b(v0[2]); a[3] = f2b(v0[3]);
        a[4] = f2b(v1[0]); a[5] = f2b(v1[1]); a[6] = f2b(v1[2]); a[7] = f2b(v1[3]);
        afrag[s] = a;
    }

    // ---- MFMA: 4 N-tiles x 2 K-steps ----
    f32x4 acc[4];
    #pragma unroll
    for (int nt = 0; nt < 4; ++nt) acc[nt] = (f32x4){0.f, 0.f, 0.f, 0.f};

    #pragma unroll
    for (int s = 0; s < 2; ++s) {
        #pragma unroll
        for (int nt = 0; nt < 4; ++nt) {
            // B fragment: same lane->k mapping as A, col = nt*16 + lr
            short8 b = *(const short8*)&WT[(nt * 16 + lr) * LDSW + 32 * s + 8 * g];
            acc[nt] = __builtin_amdgcn_mfma_f32_16x16x32_bf16(afrag[s], b, acc[nt], 0, 0, 0);
        }
    }

    // ---- Store: C/D layout col=lane&15, row=(lane>>4)*4+reg (m89-verified) ----
    #pragma unroll
    for (int nt = 0; nt < 4; ++nt) {
        #pragma unroll
        for (int j = 0; j < 4; ++j) {
            out[(size_t)(row0 + g * 4 + j) * D_TOT + n * 64 + nt * 16 + lr] = acc[nt][j];
        }
    }
}

extern "C" void kernel_launch(void* const* d_in, const int* in_sizes, int n_in,
                              void* d_out, int out_size, void* d_ws, size_t ws_size,
                              hipStream_t stream) {
    const float* inp    = (const float*)d_in[0];
    const float* blocks = (const float*)d_in[1];
    float* out          = (float*)d_out;

    dim3 grid(16384 / 128, 64);   // 128 row-tiles x 64 blocks
    block_linear_kernel<<<grid, 512, 0, stream>>>(inp, blocks, out);
}

// Round 2
// 157.743 us; speedup vs baseline: 1.0427x; 1.0427x over previous
//
#include <hip/hip_runtime.h>
#include <hip/hip_bf16.h>

// Block-diagonal matmul: out[t, n*64+e] = sum_d inp[t, n*64+d] * blocks[n, d, e]
// T=16384, 64 blocks of 64x64, fp32 in/out, bf16 MFMA compute.
//
// Design (round 2):
//  - operand-swapped MFMA: acc = mfma(Wfrag, Afrag) -> lane's 4 acc regs are 4
//    consecutive output COLUMNS of one row -> float4 stores (was 16 scalar).
//  - W^T staged to LDS in *fragment order* (lane-contiguous 16B, conflict-free),
//    picked up ONCE into 32 VGPRs; hot loop does no LDS at all.
//  - persistent WGs: 64 n-blocks x 32 WGs x 256 thr; each WG streams 8 row-tiles
//    of 64 rows with next-tile global loads prefetched ahead of compute.

typedef __attribute__((ext_vector_type(8))) short short8;   // 8 bf16 (4 VGPRs)
typedef __attribute__((ext_vector_type(4))) float f32x4;

#define D_TOT 4096
#define TILES 8          // row-tiles per WG
#define TROWS 64         // rows per tile (4 waves * 16)

__device__ __forceinline__ short f2b(float x) {
    union { __hip_bfloat16 h; short s; } u;
    u.h = __float2bfloat16(x);
    return u.s;
}

__device__ __forceinline__ short8 cvt8(f32x4 lo, f32x4 hi) {
    short8 a;
    a[0]=f2b(lo[0]); a[1]=f2b(lo[1]); a[2]=f2b(lo[2]); a[3]=f2b(lo[3]);
    a[4]=f2b(hi[0]); a[5]=f2b(hi[1]); a[6]=f2b(hi[2]); a[7]=f2b(hi[3]);
    return a;
}

__global__ __launch_bounds__(256) void block_linear_kernel(
    const float* __restrict__ inp,
    const float* __restrict__ blocks,
    float* __restrict__ out)
{
    __shared__ __align__(16) __hip_bfloat16 WF[4096];  // frag-ordered W^T, 8 KB

    const int n    = blockIdx.y;       // which 64x64 block
    const int w    = blockIdx.x;       // 0..31: which 512-row slab
    const int tid  = threadIdx.x;
    const int wave = tid >> 6;
    const int lane = tid & 63;
    const int g    = lane >> 4;        // k-group
    const int lr   = lane & 15;        // row-within-16 / frag index

    // ---- Stage W[n] into LDS, permuted into MFMA A-fragment order ----
    // frag slot (nt,s): lane l holds W^T[e = nt*16 + (l&15)][d = 32s + 8*(l>>4) + i]
    const float* Wn = blocks + (size_t)n * 4096;
    #pragma unroll
    for (int k2 = 0; k2 < 16; ++k2) {
        int idx = tid + 256 * k2;          // = d*64 + e  (coalesced global read)
        int d = idx >> 6, e = idx & 63;
        int dst = (((e >> 4) * 2 + (d >> 5)) * 64          // (nt*2+s)*64
                   + ((d >> 3) & 3) * 16 + (e & 15)) * 8   // + lane
                  + (d & 7);                               // element i
        WF[dst] = __float2bfloat16(Wn[idx]);
    }
    __syncthreads();

    // ---- Weight fragments to registers, once (conflict-free ds_read_b128) ----
    short8 wf[4][2];
    #pragma unroll
    for (int nt = 0; nt < 4; ++nt)
        #pragma unroll
        for (int s = 0; s < 2; ++s)
            wf[nt][s] = *(const short8*)&WF[((nt * 2 + s) * 64 + lane) * 8];

    // ---- Persistent row loop: 8 tiles of 64 rows, prefetch depth 1 ----
    const int rowthr = w * (TILES * TROWS) + wave * 16 + lr;   // this lane's row
    const float* pt = inp + (size_t)rowthr * D_TOT + n * 64 + 8 * g;
    float*       po = out + (size_t)rowthr * D_TOT + n * 64 + g * 4;
    const size_t step = (size_t)TROWS * D_TOT;

    f32x4 c0, c1, c2, c3, n0, n1, n2, n3;
    c0 = *(const f32x4*)(pt);
    c1 = *(const f32x4*)(pt + 4);
    c2 = *(const f32x4*)(pt + 32);
    c3 = *(const f32x4*)(pt + 36);

    #pragma unroll
    for (int t = 0; t < TILES; ++t) {
        if (t < TILES - 1) {               // issue next tile's loads first
            const float* pn = pt + (size_t)(t + 1) * step;
            n0 = *(const f32x4*)(pn);
            n1 = *(const f32x4*)(pn + 4);
            n2 = *(const f32x4*)(pn + 32);
            n3 = *(const f32x4*)(pn + 36);
        }
        short8 b0 = cvt8(c0, c1);          // k = 0..31  for this lane's row
        short8 b1 = cvt8(c2, c3);          // k = 32..63
        float* pot = po + (size_t)t * step;
        #pragma unroll
        for (int nt = 0; nt < 4; ++nt) {
            f32x4 acc = (f32x4){0.f, 0.f, 0.f, 0.f};
            acc = __builtin_amdgcn_mfma_f32_16x16x32_bf16(wf[nt][0], b0, acc, 0, 0, 0);
            acc = __builtin_amdgcn_mfma_f32_16x16x32_bf16(wf[nt][1], b1, acc, 0, 0, 0);
            // D'[e_local][row]: lane (g,lr) reg j -> out[row][nt*16 + g*4 + j]
            *(f32x4*)(pot + nt * 16) = acc;
        }
        c0 = n0; c1 = n1; c2 = n2; c3 = n3;
    }
}

extern "C" void kernel_launch(void* const* d_in, const int* in_sizes, int n_in,
                              void* d_out, int out_size, void* d_ws, size_t ws_size,
                              hipStream_t stream) {
    const float* inp    = (const float*)d_in[0];
    const float* blocks = (const float*)d_in[1];
    float* out          = (float*)d_out;

    dim3 grid(32, 64);   // 32 row-slabs x 64 blocks, 256 thr (4 waves) each
    block_linear_kernel<<<grid, 256, 0, stream>>>(inp, blocks, out);
}

// Round 4
// 136.490 us; speedup vs baseline: 1.2050x; 1.1557x over previous
//
#include <hip/hip_runtime.h>
#include <hip/hip_bf16.h>

// Block-diagonal matmul: out[t, n*64+e] = sum_d inp[t, n*64+d] * blocks[n, d, e]
// T=16384, 64 blocks of 64x64, fp32 in/out, bf16 MFMA compute.
//
// Round 3 (fixed compile: 'short4' collides with HIP vector types -> bf16x4):
// 1KB-contiguous global access on BOTH streams (page-granularity fix).
//  - WG = 256 thr (4 waves) owns 4 consecutive blocks (1KB col span) x 256 rows,
//    processed as 8 tiles of 32 rows.
//  - loads: 1 instr = 1 row's 1KB span (lane l -> col l*4), reg-staged, cvt bf16,
//    XOR-swizzled LDS (chunk ^= row&7) -> conflict-free ds_read_b128 fragments.
//  - stores: acc -> swizzled LDS bounce -> row-linear readback -> 1KB-contiguous
//    global_store_dwordx4.
//  - T14 async-stage: tile t+1 loads issued after compute(t), written to LDS
//    during store phase; 2 barriers/tile.
//  - weights in registers (operand-swapped MFMA, layout validated in round 2).

typedef __attribute__((ext_vector_type(8))) short short8;   // 8 bf16
typedef __attribute__((ext_vector_type(4))) short bf16x4;   // 4 bf16
typedef __attribute__((ext_vector_type(4))) float f32x4;

#define D_TOT  4096
#define TROWS  32        // rows per tile
#define NTILES 8         // tiles per WG (WG covers 256 rows)

__device__ __forceinline__ short f2b(float x) {
    union { __hip_bfloat16 h; short s; } u;
    u.h = __float2bfloat16(x);
    return u.s;
}

__global__ __launch_bounds__(256, 3) void block_linear_kernel(
    const float* __restrict__ inp,
    const float* __restrict__ blocks,
    float* __restrict__ out)
{
    // IN: bf16 [32 rows][256 cols] = 512B/row, chunk16-swizzled   (16 KB)
    // OUT: fp32 [32 rows][256 cols] = 1KB/row, chunk16-swizzled   (32 KB)
    __shared__ __align__(16) unsigned char INB[TROWS * 512];
    __shared__ __align__(16) unsigned char OUTB[TROWS * 1024];

    const int slab = blockIdx.x;        // 0..63  : 256-row slab
    const int ngrp = blockIdx.y;        // 0..15  : group of 4 blocks
    const int tid  = threadIdx.x;
    const int w    = tid >> 6;          // wave = block-within-group
    const int lane = tid & 63;
    const int g    = lane >> 4;         // k-group
    const int lr   = lane & 15;

    // ---- weights for this wave's block -> frag registers (init-only gather) ----
    // frag (nt,s): lane (g,lr) holds W[d = s*32+8g+i][e = nt*16+lr], i=0..7
    const int n = ngrp * 4 + w;
    const float* Wn = blocks + (size_t)n * 4096;
    short8 wf[4][2];
    #pragma unroll
    for (int nt = 0; nt < 4; ++nt)
        #pragma unroll
        for (int s = 0; s < 2; ++s) {
            short8 a;
            #pragma unroll
            for (int i = 0; i < 8; ++i)
                a[i] = f2b(Wn[(s * 32 + 8 * g + i) * 64 + nt * 16 + lr]);
            wf[nt][s] = a;
        }

    const size_t row0 = (size_t)slab * (NTILES * TROWS);
    const float* gin  = inp + row0 * D_TOT + ngrp * 256;
    float*       gout = out + row0 * D_TOT + ngrp * 256;

    // ---- prologue: stage tile 0 (wave w stages rows w, w+4, ..., w+28) ----
    f32x4 pf[8];
    #pragma unroll
    for (int j = 0; j < 8; ++j)
        pf[j] = *(const f32x4*)(gin + (size_t)(w + 4 * j) * D_TOT + lane * 4);
    #pragma unroll
    for (int j = 0; j < 8; ++j) {
        int r = w + 4 * j;
        bf16x4 v;
        v[0] = f2b(pf[j][0]); v[1] = f2b(pf[j][1]);
        v[2] = f2b(pf[j][2]); v[3] = f2b(pf[j][3]);
        // bf16 chunk c = lane>>1 (16B), half = lane&1; phys chunk = c ^ (r&7)
        *(bf16x4*)&INB[r * 512 + (((lane >> 1) ^ (r & 7)) << 4) + ((lane & 1) << 3)] = v;
    }

    for (int t = 0; t < NTILES; ++t) {
        __syncthreads();   // IN(t) ready; OUT(t-1) fully consumed

        // ---- 1. compute: B-frags from swizzled IN, MFMA into acc ----
        f32x4 acc[2][4];
        #pragma unroll
        for (int rg = 0; rg < 2; ++rg)
            #pragma unroll
            for (int nt = 0; nt < 4; ++nt)
                acc[rg][nt] = (f32x4){0.f, 0.f, 0.f, 0.f};

        #pragma unroll
        for (int rg = 0; rg < 2; ++rg) {
            const int r = rg * 16 + lr;
            #pragma unroll
            for (int s = 0; s < 2; ++s) {
                const int c = w * 8 + s * 4 + g;      // block w, k-chunk (s,g)
                short8 bfrag = *(const short8*)&INB[r * 512 + ((c ^ (r & 7)) << 4)];
                #pragma unroll
                for (int nt = 0; nt < 4; ++nt)
                    acc[rg][nt] = __builtin_amdgcn_mfma_f32_16x16x32_bf16(
                        wf[nt][s], bfrag, acc[rg][nt], 0, 0, 0);
            }
        }

        // ---- 2. issue next tile's global loads (latency hides under 3-5) ----
        if (t + 1 < NTILES) {
            const float* gi = gin + (size_t)(t + 1) * TROWS * D_TOT;
            #pragma unroll
            for (int j = 0; j < 8; ++j)
                pf[j] = *(const f32x4*)(gi + (size_t)(w + 4 * j) * D_TOT + lane * 4);
        }

        // ---- 3. bounce acc -> swizzled OUT ----
        #pragma unroll
        for (int rg = 0; rg < 2; ++rg) {
            const int r = rg * 16 + lr;
            #pragma unroll
            for (int nt = 0; nt < 4; ++nt) {
                const int c = w * 16 + nt * 4 + g;    // fp32 chunk16 index 0..63
                *(f32x4*)&OUTB[r * 1024 + ((c ^ (r & 7)) << 4)] = acc[rg][nt];
            }
        }

        __syncthreads();   // 4. OUT(t) complete; IN(t) free to overwrite

        // ---- 5. store OUT(t) row-linear (1KB/instr) + stage IN(t+1) ----
        float* go = gout + (size_t)t * TROWS * D_TOT;
        #pragma unroll
        for (int j = 0; j < 8; ++j) {
            const int r = w + 4 * j;
            f32x4 v = *(const f32x4*)&OUTB[r * 1024 + ((lane ^ (r & 7)) << 4)];
            *(f32x4*)(go + (size_t)r * D_TOT + lane * 4) = v;
        }
        if (t + 1 < NTILES) {
            #pragma unroll
            for (int j = 0; j < 8; ++j) {
                const int r = w + 4 * j;
                bf16x4 v;
                v[0] = f2b(pf[j][0]); v[1] = f2b(pf[j][1]);
                v[2] = f2b(pf[j][2]); v[3] = f2b(pf[j][3]);
                *(bf16x4*)&INB[r * 512 + (((lane >> 1) ^ (r & 7)) << 4) + ((lane & 1) << 3)] = v;
            }
        }
    }
}

extern "C" void kernel_launch(void* const* d_in, const int* in_sizes, int n_in,
                              void* d_out, int out_size, void* d_ws, size_t ws_size,
                              hipStream_t stream) {
    const float* inp    = (const float*)d_in[0];
    const float* blocks = (const float*)d_in[1];
    float* out          = (float*)d_out;

    dim3 grid(64, 16);   // 64 row-slabs x 16 block-groups
    block_linear_kernel<<<grid, 256, 0, stream>>>(inp, blocks, out);
}